// Round 13
// baseline (125.443 us; speedup 1.0000x reference)
//
#include <hip/hip_runtime.h>
#include <stdint.h>

#define N_ANG    360
#define N_DET    357
#define FILT_LEN 713
#define N_COLS   (N_ANG * N_DET)      // 128520 < 2^17
#define N_PIXK   65536
#define NNZK     8388608
#define NB       4

#define NPART    256
#define PART_SH  8                    // partition = row >> 8
#define PART_PIX 256                  // pixels per partition
#define CHUNK    8192                 // nnz per chunk/block in binning
#define NCHUNK   (NNZK / CHUNK)       // 1024, exact
#define P1_T     256
#define P2_T     1024
#define P2_PER_T (CHUNK / P2_T)       // 8

#define ACC_SPLIT 8                   // sub-blocks per partition in accum
#define CAPE      36864u              // entries/partition = mean 32768 + 22 sigma

#define FPS      67108864.0f          // 2^26 fixed point (tier-2 path)
#define FPS_INV  (1.0f / 67108864.0f)
#define FPS20     1048576.0f          // 2^20 fixed point (pre-multiplied path)
#define FPS20_INV (1.0f / 1048576.0f)

// LDS-only barrier: waits LDS ops, leaves global loads (vmcnt) IN FLIGHT.
// HIP __syncthreads() would emit s_waitcnt vmcnt(0) and drain the X gathers.
__device__ __forceinline__ void bar_lds() {
    asm volatile("s_waitcnt lgkmcnt(0)" ::: "memory");
    __builtin_amdgcn_s_barrier();
}

// ---------------------------------------------------------------------------
// Stage 1: r = sin_fan * cos, SAME conv len-713 along detector axis.
// Block 0 also zeroes galloc (folds the zero kernel's launch away).
// ---------------------------------------------------------------------------
__global__ void filt_kernel(const float* __restrict__ sin_fan,
                            const float* __restrict__ cosv,
                            const float* __restrict__ filt,
                            float* __restrict__ X,
                            unsigned* __restrict__ galloc) {
    __shared__ float s_r[N_DET];
    __shared__ float s_f[FILT_LEN];
    const int blk = blockIdx.x;            // b*N_ANG + a
    const int b   = blk / N_ANG;
    const int a   = blk % N_ANG;
    const int tid = threadIdx.x;

    if (blk == 0 && tid < NPART) galloc[tid] = 0u;

    for (int i = tid; i < N_DET; i += blockDim.x)
        s_r[i] = sin_fan[(size_t)(b * N_ANG + a) * N_DET + i] * cosv[a * N_DET + i];
    for (int i = tid; i < FILT_LEN; i += blockDim.x)
        s_f[i] = filt[i];
    __syncthreads();

    for (int d = tid; d < N_DET; d += blockDim.x) {
        float acc = 0.f;
        const float* fp = &s_f[356 - d];
        #pragma unroll 7
        for (int j = 0; j < N_DET; ++j)
            acc = fmaf(s_r[j], fp[j], acc);
        X[(size_t)(a * N_DET + d) * NB + b] = acc;
    }
}

// ---------------------------------------------------------------------------
// Single-pass binning with pre-multiplication, gathers OVERLAPPED with the
// scan: all 8 X4[col] gathers issue in the input phase; the scan runs on
// raw s_barrier + lgkmcnt-only waits (bar_lds) so the gathers stay in
// flight across ~16 barriers; the pack phase consumes them (compiler
// inserts the vmcnt wait there). Output phase is then a pure LDS-read ->
// coalesced-run store with no gather chain.
// Entry u64: [rl:8][i3:14][i2:14][i1:14][i0:14] at 2^20 scale (|i|<6.2k).
// ---------------------------------------------------------------------------
__global__ void __launch_bounds__(1024)
bin1p_kernel(const float* __restrict__ A_vals,
             const int*   __restrict__ A_rows,
             const int*   __restrict__ A_cols,
             const float4* __restrict__ X4,
             unsigned* __restrict__ galloc,
             unsigned long long* __restrict__ bins) {
    __shared__ unsigned long long stage[CHUNK];   // 64 KB
    __shared__ unsigned char spart[CHUNK];        // 8 KB
    __shared__ unsigned loff[NPART], cnt[NPART], goff[NPART];
    const int chunk = blockIdx.x, tid = threadIdx.x;   // 1024
    if (tid < NPART) { cnt[tid] = 0; loff[tid] = 0; }

    const int base = chunk * CHUNK;
    const int4*   r4 = (const int4*)(A_rows + base);
    const int4*   c4 = (const int4*)(A_cols + base);
    const float4* v4 = (const float4*)(A_vals + base);

    // ---- input phase: loads + gather issue (cols die after this) ----
    const int4 ra = r4[tid * 2], rb = r4[tid * 2 + 1];
    const int4 ca = c4[tid * 2], cb = c4[tid * 2 + 1];
    const float4 va = v4[tid * 2], vb = v4[tid * 2 + 1];
    const float4 x0 = X4[(unsigned)ca.x];
    const float4 x1 = X4[(unsigned)ca.y];
    const float4 x2 = X4[(unsigned)ca.z];
    const float4 x3 = X4[(unsigned)ca.w];
    const float4 x4_ = X4[(unsigned)cb.x];
    const float4 x5 = X4[(unsigned)cb.y];
    const float4 x6 = X4[(unsigned)cb.z];
    const float4 x7 = X4[(unsigned)cb.w];

    bar_lds();                                  // cnt/loff zero visible

    // ---- histogram (LDS atomics; gathers still in flight) ----
    atomicAdd(&loff[ra.x >> PART_SH], 1u);
    atomicAdd(&loff[ra.y >> PART_SH], 1u);
    atomicAdd(&loff[ra.z >> PART_SH], 1u);
    atomicAdd(&loff[ra.w >> PART_SH], 1u);
    atomicAdd(&loff[rb.x >> PART_SH], 1u);
    atomicAdd(&loff[rb.y >> PART_SH], 1u);
    atomicAdd(&loff[rb.z >> PART_SH], 1u);
    atomicAdd(&loff[rb.w >> PART_SH], 1u);
    bar_lds();

    // ---- reserve global run space + exclusive scan (LDS-only barriers) ----
    unsigned hv = 0, gbase = 0;
    if (tid < NPART) {
        hv = loff[tid];
        gbase = atomicAdd(&galloc[tid], hv);    // global atomic, stays in flight
    }
    for (int off = 1; off < NPART; off <<= 1) {
        unsigned t = 0;
        if (tid < NPART && tid >= off) t = loff[tid - off];
        bar_lds();
        if (tid < NPART) loff[tid] += t;
        bar_lds();
    }
    if (tid < NPART) {
        loff[tid] -= hv;                        // inclusive -> exclusive
        goff[tid] = tid * CAPE + gbase;         // vmcnt wait auto-inserted here
    }
    bar_lds();

    // ---- pack + stage (consumes gathers; vmcnt waits inserted here) ----
#define PACK_STAGE(rowv, valv, xv)                                            \
    {                                                                         \
        const int p_ = (rowv) >> PART_SH;                                     \
        const unsigned long long rl_ =                                        \
            (unsigned long long)((rowv) & (PART_PIX - 1));                    \
        const float c0_ = fminf(fmaxf((valv) * (xv).x * FPS20, -8192.f), 8191.f); \
        const float c1_ = fminf(fmaxf((valv) * (xv).y * FPS20, -8192.f), 8191.f); \
        const float c2_ = fminf(fmaxf((valv) * (xv).z * FPS20, -8192.f), 8191.f); \
        const float c3_ = fminf(fmaxf((valv) * (xv).w * FPS20, -8192.f), 8191.f); \
        const unsigned q0_ = (unsigned)__float2int_rn(c0_) & 0x3FFFu;         \
        const unsigned q1_ = (unsigned)__float2int_rn(c1_) & 0x3FFFu;         \
        const unsigned q2_ = (unsigned)__float2int_rn(c2_) & 0x3FFFu;         \
        const unsigned q3_ = (unsigned)__float2int_rn(c3_) & 0x3FFFu;         \
        const unsigned long long e_ =                                         \
            (rl_ << 56) | ((unsigned long long)q3_ << 42) |                   \
            ((unsigned long long)q2_ << 28) | ((unsigned long long)q1_ << 14) |\
            (unsigned long long)q0_;                                          \
        const unsigned rank_ = atomicAdd(&cnt[p_], 1u);                       \
        const unsigned pos_ = loff[p_] + rank_;                               \
        stage[pos_] = e_;                                                     \
        spart[pos_] = (unsigned char)p_;                                      \
    }

    PACK_STAGE(ra.x, va.x, x0);
    PACK_STAGE(ra.y, va.y, x1);
    PACK_STAGE(ra.z, va.z, x2);
    PACK_STAGE(ra.w, va.w, x3);
    PACK_STAGE(rb.x, vb.x, x4_);
    PACK_STAGE(rb.y, vb.y, x5);
    PACK_STAGE(rb.z, vb.z, x6);
    PACK_STAGE(rb.w, vb.w, x7);
#undef PACK_STAGE
    bar_lds();

    // ---- output: pure LDS read -> contiguous-run global store ----
    #pragma unroll
    for (int k = 0; k < P2_PER_T; ++k) {
        const int i = k * P2_T + tid;
        const unsigned p = spart[i];
        bins[goff[p] + (unsigned)i - loff[p]] = stage[i];
    }
}

// ---------------------------------------------------------------------------
// Gather-free accum: coalesced u64 stream, decode 14-bit fields, 2 native
// ds_add_u64 per entry (2 channels packed per u64 at 2^20).
// ---------------------------------------------------------------------------
__device__ __forceinline__ int sx14(unsigned long long e, int sh) {
    return ((int)((((unsigned)(e >> sh)) & 0x3FFFu) << 18)) >> 18;
}

__global__ void __launch_bounds__(1024)
accum_pm_kernel(const unsigned long long* __restrict__ bins,
                const unsigned* __restrict__ galloc,
                unsigned long long* __restrict__ partial) {
    __shared__ unsigned long long iacc[2 * PART_PIX];   // 4 KB
    const int bp = blockIdx.x;
    const int p = bp >> 3, j = bp & 7;
    const int tid = threadIdx.x;
    if (tid < 2 * PART_PIX) iacc[tid] = 0ULL;
    __syncthreads();

    const unsigned c = galloc[p];
    const unsigned q = (c + ACC_SPLIT - 1) / ACC_SPLIT;
    const unsigned qs = j * q;
    const unsigned qe = min(qs + q, c);
    const unsigned long long* b8 = bins + (size_t)p * CAPE;

    #pragma unroll 4
    for (unsigned i = qs + tid; i < qe; i += 1024) {
        const unsigned long long e = b8[i];
        const unsigned rl = (unsigned)(e >> 56);
        const int i0 = sx14(e, 0);
        const int i1 = sx14(e, 14);
        const int i2 = sx14(e, 28);
        const int i3 = sx14(e, 42);
        const unsigned long long w0 =
            ((unsigned long long)(unsigned)i1 << 32) + (unsigned long long)(unsigned)i0;
        const unsigned long long w1 =
            ((unsigned long long)(unsigned)i3 << 32) + (unsigned long long)(unsigned)i2;
        atomicAdd(&iacc[rl], w0);
        atomicAdd(&iacc[PART_PIX + rl], w1);
    }
    __syncthreads();

    if (tid < 2 * PART_PIX)
        partial[((size_t)j * NPART + p) * (2 * PART_PIX) + tid] = iacc[tid];
}

// ---------------------------------------------------------------------------
// Sum the 8 u64 partials, decode both packed channels, clip, write.
// ---------------------------------------------------------------------------
__global__ void reduce8_kernel(const unsigned long long* __restrict__ partial,
                               float* __restrict__ out, float inv_scale) {
    const int g = blockIdx.x * blockDim.x + threadIdx.x;  // 0 .. 256*512-1
    const int p = g >> 9, t = g & 511;
    const int pair = t >> 8, rl = t & (PART_PIX - 1);
    unsigned long long s = 0;
    #pragma unroll
    for (int j = 0; j < ACC_SPLIT; ++j)
        s += partial[((size_t)j * NPART + p) * (2 * PART_PIX) + t];
    const float clo = (float)(int)(unsigned)(s & 0xffffffffULL) * inv_scale;
    const float chi = (float)(int)(unsigned)(s >> 32)           * inv_scale;
    const int ch0 = pair * 2, ch1 = pair * 2 + 1;
    out[(size_t)ch0 * N_PIXK + p * PART_PIX + rl] = fminf(fmaxf(clo, 0.f), 1.f);
    out[(size_t)ch1 * N_PIXK + p * PART_PIX + rl] = fminf(fmaxf(chi, 0.f), 1.f);
}

// ===================== fallback tier 2: round-8 sort path ==================
__global__ void filt2_kernel(const float* __restrict__ sin_fan,
                             const float* __restrict__ cosv,
                             const float* __restrict__ filt,
                             float* __restrict__ X) {
    __shared__ float s_r[N_DET];
    __shared__ float s_f[FILT_LEN];
    const int blk = blockIdx.x;
    const int b   = blk / N_ANG;
    const int a   = blk % N_ANG;
    const int tid = threadIdx.x;
    for (int i = tid; i < N_DET; i += blockDim.x)
        s_r[i] = sin_fan[(size_t)(b * N_ANG + a) * N_DET + i] * cosv[a * N_DET + i];
    for (int i = tid; i < FILT_LEN; i += blockDim.x)
        s_f[i] = filt[i];
    __syncthreads();
    for (int d = tid; d < N_DET; d += blockDim.x) {
        float acc = 0.f;
        const float* fp = &s_f[356 - d];
        #pragma unroll 7
        for (int j = 0; j < N_DET; ++j)
            acc = fmaf(s_r[j], fp[j], acc);
        X[(size_t)(a * N_DET + d) * NB + b] = acc;
    }
}

__global__ void hist_kernel(const int* __restrict__ A_rows,
                            unsigned* __restrict__ counts) {
    __shared__ unsigned h[NPART];
    const int chunk = blockIdx.x, tid = threadIdx.x;   // 256
    h[tid] = 0;
    __syncthreads();
    const int4* r4 = (const int4*)(A_rows + chunk * CHUNK);
    #pragma unroll
    for (int k = 0; k < 8; ++k) {
        const int4 rv = r4[tid * 8 + k];
        atomicAdd(&h[rv.x >> PART_SH], 1u);
        atomicAdd(&h[rv.y >> PART_SH], 1u);
        atomicAdd(&h[rv.z >> PART_SH], 1u);
        atomicAdd(&h[rv.w >> PART_SH], 1u);
    }
    __syncthreads();
    counts[chunk * NPART + tid] = h[tid];
}

__global__ void scanA_kernel(unsigned* __restrict__ counts,
                             unsigned* __restrict__ ptot) {
    const int p = blockIdx.x, tid = threadIdx.x;   // 256
    unsigned v[4], s = 0;
    #pragma unroll
    for (int k = 0; k < 4; ++k) {
        v[k] = counts[(size_t)(tid * 4 + k) * NPART + p];
        s += v[k];
    }
    __shared__ unsigned sc[256];
    sc[tid] = s;
    __syncthreads();
    for (int off = 1; off < 256; off <<= 1) {
        unsigned t = (tid >= off) ? sc[tid - off] : 0u;
        __syncthreads();
        sc[tid] += t;
        __syncthreads();
    }
    unsigned run = sc[tid] - s;
    if (tid == 255) ptot[p] = sc[255];
    #pragma unroll
    for (int k = 0; k < 4; ++k) {
        counts[(size_t)(tid * 4 + k) * NPART + p] = run;
        run += v[k];
    }
}

__global__ void scanB_kernel(const unsigned* __restrict__ ptot,
                             unsigned* __restrict__ part_base) {
    const int tid = threadIdx.x;                   // 256
    unsigned s = ptot[tid];
    __shared__ unsigned sc[256];
    sc[tid] = s;
    __syncthreads();
    for (int off = 1; off < 256; off <<= 1) {
        unsigned t = (tid >= off) ? sc[tid - off] : 0u;
        __syncthreads();
        sc[tid] += t;
        __syncthreads();
    }
    part_base[tid] = sc[tid] - s;
    if (tid == 255) part_base[256] = sc[255];
}

__global__ void __launch_bounds__(1024)
bin_kernel(const float* __restrict__ A_vals,
           const int*   __restrict__ A_rows,
           const int*   __restrict__ A_cols,
           const unsigned* __restrict__ offsets,
           const unsigned* __restrict__ part_base,
           uint2* __restrict__ bins) {
    __shared__ uint2 stage[CHUNK];
    __shared__ unsigned char spart[CHUNK];
    __shared__ unsigned loff[NPART], cnt[NPART], goff[NPART];
    const int chunk = blockIdx.x, tid = threadIdx.x;
    if (tid < NPART) cnt[tid] = 0;
    if (tid >= NPART && tid < 2 * NPART) loff[tid - NPART] = 0;
    __syncthreads();

    const int base = chunk * CHUNK;
    const int4*   r4 = (const int4*)(A_rows + base);
    const int4*   c4 = (const int4*)(A_cols + base);
    const float4* v4 = (const float4*)(A_vals + base);
    int rows[P2_PER_T];
    {
        const int4 ra = r4[tid * 2], rb = r4[tid * 2 + 1];
        rows[0] = ra.x; rows[1] = ra.y; rows[2] = ra.z; rows[3] = ra.w;
        rows[4] = rb.x; rows[5] = rb.y; rows[6] = rb.z; rows[7] = rb.w;
    }
    #pragma unroll
    for (int k = 0; k < P2_PER_T; ++k)
        atomicAdd(&loff[rows[k] >> PART_SH], 1u);
    __syncthreads();

    unsigned hv = 0;
    if (tid < NPART) hv = loff[tid];
    for (int off = 1; off < NPART; off <<= 1) {
        unsigned t = 0;
        if (tid < NPART && tid >= off) t = loff[tid - off];
        __syncthreads();
        if (tid < NPART) loff[tid] += t;
        __syncthreads();
    }
    if (tid < NPART) {
        loff[tid] -= hv;
        goff[tid] = part_base[tid] + offsets[chunk * NPART + tid];
    }
    __syncthreads();

    {
        const int4   ca = c4[tid * 2], cb = c4[tid * 2 + 1];
        const float4 va = v4[tid * 2], vb = v4[tid * 2 + 1];
        const unsigned cols[P2_PER_T] = {
            (unsigned)ca.x, (unsigned)ca.y, (unsigned)ca.z, (unsigned)ca.w,
            (unsigned)cb.x, (unsigned)cb.y, (unsigned)cb.z, (unsigned)cb.w };
        const float vals[P2_PER_T] = { va.x, va.y, va.z, va.w,
                                       vb.x, vb.y, vb.z, vb.w };
        #pragma unroll
        for (int k = 0; k < P2_PER_T; ++k) {
            const int row = rows[k];
            const int p = row >> PART_SH;
            const unsigned rank = atomicAdd(&cnt[p], 1u);
            const unsigned pos = loff[p] + rank;
            stage[pos] = make_uint2(__float_as_uint(vals[k]),
                                    ((unsigned)(row & (PART_PIX - 1)) << 17) | cols[k]);
            spart[pos] = (unsigned char)p;
        }
    }
    __syncthreads();

    #pragma unroll
    for (int k = 0; k < P2_PER_T; ++k) {
        const int i = k * P2_T + tid;
        const unsigned p = spart[i];
        const unsigned glob = goff[p] + (unsigned)i - loff[p];
        bins[glob] = stage[i];
    }
}

__global__ void __launch_bounds__(1024)
accum8_kernel(const uint2* __restrict__ bins,
              const unsigned* __restrict__ part_base,
              const float4* __restrict__ X4,
              unsigned long long* __restrict__ partial) {
    __shared__ unsigned long long iacc[2 * PART_PIX];
    const int bp = blockIdx.x;
    const int p = bp >> 3, j = bp & 7;
    const int tid = threadIdx.x;
    if (tid < 2 * PART_PIX) iacc[tid] = 0ULL;
    __syncthreads();

    const unsigned s = part_base[p], e = part_base[p + 1];
    const unsigned len = e - s;
    const unsigned q = (len + ACC_SPLIT - 1) / ACC_SPLIT;
    const unsigned qs = s + j * q;
    const unsigned qe = min(qs + q, e);

    #pragma unroll 4
    for (unsigned i = qs + tid; i < qe; i += 1024) {
        const uint2 en = bins[i];
        const float v = __uint_as_float(en.x);
        const unsigned col = en.y & 0x1FFFFu;
        const unsigned rl  = en.y >> 17;
        const float4 x = X4[col];
        const int i0 = __float2int_rn(v * x.x * FPS);
        const int i1 = __float2int_rn(v * x.y * FPS);
        const int i2 = __float2int_rn(v * x.z * FPS);
        const int i3 = __float2int_rn(v * x.w * FPS);
        const unsigned long long w0 =
            ((unsigned long long)(unsigned)i1 << 32) + (unsigned long long)(unsigned)i0;
        const unsigned long long w1 =
            ((unsigned long long)(unsigned)i3 << 32) + (unsigned long long)(unsigned)i2;
        atomicAdd(&iacc[rl], w0);
        atomicAdd(&iacc[PART_PIX + rl], w1);
    }
    __syncthreads();

    if (tid < 2 * PART_PIX)
        partial[((size_t)j * NPART + p) * (2 * PART_PIX) + tid] = iacc[tid];
}

// ===================== fallback tier 3: replica atomic path ================
#define NXCD 8
#define FP_SCALE 16777216.0f
#define FP_INV   (1.0 / 16777216.0)
__global__ void zero_u64_kernel(unsigned long long* __restrict__ p, int n) {
    int i = blockIdx.x * blockDim.x + threadIdx.x;
    if (i < n) p[i] = 0ULL;
}
__device__ __forceinline__ unsigned get_xcc_id() {
    unsigned x;
    asm volatile("s_getreg_b32 %0, hwreg(HW_REG_XCC_ID, 0, 4)" : "=s"(x));
    return x & (NXCD - 1);
}
__global__ void scatter_kernel(const float*  __restrict__ A_vals,
                               const int*    __restrict__ A_rows,
                               const int*    __restrict__ A_cols,
                               const float4* __restrict__ X4,
                               unsigned long long* __restrict__ rep) {
    unsigned long long* myrep = rep + (size_t)get_xcc_id() * N_PIXK * 2;
    const int stride = gridDim.x * blockDim.x;
    for (int i = blockIdx.x * blockDim.x + threadIdx.x; i < NNZK; i += stride) {
        const float v = A_vals[i];
        const float4 x = X4[A_cols[i]];
        const int r = A_rows[i];
        const int i0 = __float2int_rn(v * x.x * FP_SCALE);
        const int i1 = __float2int_rn(v * x.y * FP_SCALE);
        const int i2 = __float2int_rn(v * x.z * FP_SCALE);
        const int i3 = __float2int_rn(v * x.w * FP_SCALE);
        const unsigned long long w0 =
            ((unsigned long long)(unsigned)i1 << 32) + (unsigned long long)(unsigned)i0;
        const unsigned long long w1 =
            ((unsigned long long)(unsigned)i3 << 32) + (unsigned long long)(unsigned)i2;
        __hip_atomic_fetch_add(&myrep[(size_t)r * 2 + 0], w0,
                               __ATOMIC_RELAXED, __HIP_MEMORY_SCOPE_WORKGROUP);
        __hip_atomic_fetch_add(&myrep[(size_t)r * 2 + 1], w1,
                               __ATOMIC_RELAXED, __HIP_MEMORY_SCOPE_WORKGROUP);
    }
}
__global__ void reduce_clip_kernel(const unsigned long long* __restrict__ rep,
                                   float* __restrict__ out) {
    const int p = blockIdx.x * blockDim.x + threadIdx.x;
    if (p >= N_PIXK) return;
    unsigned long long s0 = 0, s1 = 0;
    #pragma unroll
    for (int x = 0; x < NXCD; ++x) {
        s0 += rep[((size_t)x * N_PIXK + p) * 2 + 0];
        s1 += rep[((size_t)x * N_PIXK + p) * 2 + 1];
    }
    const float c0 = (float)((double)(int)(unsigned)(s0 & 0xffffffffULL) * FP_INV);
    const float c1 = (float)((double)(int)(unsigned)(s0 >> 32)           * FP_INV);
    const float c2 = (float)((double)(int)(unsigned)(s1 & 0xffffffffULL) * FP_INV);
    const float c3 = (float)((double)(int)(unsigned)(s1 >> 32)           * FP_INV);
    out[0 * N_PIXK + p] = fminf(fmaxf(c0, 0.f), 1.f);
    out[1 * N_PIXK + p] = fminf(fmaxf(c1, 0.f), 1.f);
    out[2 * N_PIXK + p] = fminf(fmaxf(c2, 0.f), 1.f);
    out[3 * N_PIXK + p] = fminf(fmaxf(c3, 0.f), 1.f);
}

extern "C" void kernel_launch(void* const* d_in, const int* in_sizes, int n_in,
                              void* d_out, int out_size, void* d_ws, size_t ws_size,
                              hipStream_t stream) {
    const float* sin_fan = (const float*)d_in[0];
    const float* cosv    = (const float*)d_in[1];
    const float* filt    = (const float*)d_in[2];
    const float* A_vals  = (const float*)d_in[3];
    const int*   A_rows  = (const int*)d_in[4];
    const int*   A_cols  = (const int*)d_in[5];
    float* out = (float*)d_out;

    const size_t MB = 1024 * 1024;
    // --- tier 1: pre-multiplied single-pass layout ---
    const size_t off_alloc = 2 * MB;
    const size_t off_part  = off_alloc + 65536;
    const size_t off_bins  = off_part +
        (size_t)ACC_SPLIT * NPART * (2 * PART_PIX) * sizeof(unsigned long long);
    const size_t need_1p   = off_bins +
        (size_t)NPART * CAPE * sizeof(unsigned long long);
    // --- tier 2 (round-8) layout ---
    const size_t need_sort  = 3 * MB + 4096 + (size_t)NNZK * sizeof(uint2);
    const size_t need_split = need_sort +
        (size_t)ACC_SPLIT * NPART * (2 * PART_PIX) * sizeof(unsigned long long);

    if (ws_size >= need_1p) {
        float*    X      = (float*)d_ws;
        unsigned* galloc = (unsigned*)((char*)d_ws + off_alloc);
        unsigned long long* partial =
            (unsigned long long*)((char*)d_ws + off_part);
        unsigned long long* bins =
            (unsigned long long*)((char*)d_ws + off_bins);

        filt_kernel<<<NB * N_ANG, 256, 0, stream>>>(sin_fan, cosv, filt, X,
                                                    galloc);
        bin1p_kernel<<<NCHUNK, P2_T, 0, stream>>>(A_vals, A_rows, A_cols,
                                                  (const float4*)X, galloc, bins);
        accum_pm_kernel<<<NPART * ACC_SPLIT, 1024, 0, stream>>>(
            bins, galloc, partial);
        reduce8_kernel<<<(NPART * 2 * PART_PIX) / 1024, 1024, 0, stream>>>(
            partial, out, FPS20_INV);
    } else if (ws_size >= need_split) {
        float*    X      = (float*)d_ws;
        unsigned* counts = (unsigned*)((char*)d_ws + 2 * MB);
        unsigned* pbase  = (unsigned*)((char*)d_ws + 3 * MB);
        unsigned* ptot   = (unsigned*)((char*)d_ws + 3 * MB + 2048);
        uint2*    bins   = (uint2*)((char*)d_ws + 3 * MB + 4096);
        unsigned long long* partial =
            (unsigned long long*)((char*)d_ws + need_sort);

        filt2_kernel<<<NB * N_ANG, 256, 0, stream>>>(sin_fan, cosv, filt, X);
        hist_kernel<<<NCHUNK, P1_T, 0, stream>>>(A_rows, counts);
        scanA_kernel<<<NPART, 256, 0, stream>>>(counts, ptot);
        scanB_kernel<<<1, 256, 0, stream>>>(ptot, pbase);
        bin_kernel<<<NCHUNK, P2_T, 0, stream>>>(A_vals, A_rows, A_cols, counts,
                                                pbase, bins);
        accum8_kernel<<<NPART * ACC_SPLIT, 1024, 0, stream>>>(
            bins, pbase, (const float4*)X, partial);
        reduce8_kernel<<<(NPART * 2 * PART_PIX) / 1024, 1024, 0, stream>>>(
            partial, out, FPS_INV);
    } else {
        unsigned long long* rep = (unsigned long long*)d_ws;
        const size_t rep_bytes = (size_t)NXCD * N_PIXK * 2 * sizeof(unsigned long long);
        float* X = (float*)((char*)d_ws + rep_bytes);
        const int nrep = NXCD * N_PIXK * 2;
        zero_u64_kernel<<<(nrep + 255) / 256, 256, 0, stream>>>(rep, nrep);
        filt2_kernel<<<NB * N_ANG, 256, 0, stream>>>(sin_fan, cosv, filt, X);
        scatter_kernel<<<4096, 256, 0, stream>>>(A_vals, A_rows, A_cols,
                                                 (const float4*)X, rep);
        reduce_clip_kernel<<<(N_PIXK + 255) / 256, 256, 0, stream>>>(rep, out);
    }
}

// Round 14
// 113.032 us; speedup vs baseline: 1.1098x; 1.1098x over previous
//
#include <hip/hip_runtime.h>
#include <stdint.h>

#define N_ANG    360
#define N_DET    357
#define FILT_LEN 713
#define N_COLS   (N_ANG * N_DET)      // 128520 < 2^17
#define N_PIXK   65536
#define NNZK     8388608
#define NB       4

#define NPART    256
#define PART_SH  8                    // partition = row >> 8
#define PART_PIX 256                  // pixels per partition
#define CHUNK    8192                 // nnz per chunk/block in binning
#define NCHUNK   (NNZK / CHUNK)       // 1024, exact
#define P1_T     256
#define P2_T     1024
#define P2_PER_T (CHUNK / P2_T)       // 8

#define ACC_SPLIT 8                   // sub-blocks per partition in accum
#define CAPE      36864u              // entries/partition = mean 32768 + 22 sigma

#define FPS      67108864.0f          // 2^26 fixed point (tier-2 path)
#define FPS_INV  (1.0f / 67108864.0f)
#define FPS20     1048576.0f          // 2^20 fixed point (pre-multiplied path)
#define FPS20_INV (1.0f / 1048576.0f)

// ---------------------------------------------------------------------------
// Stage 1: r = sin_fan * cos, SAME conv len-713 along detector axis.
// Block 0 also zeroes galloc (folds the zero kernel's launch away).
// ---------------------------------------------------------------------------
__global__ void filt_kernel(const float* __restrict__ sin_fan,
                            const float* __restrict__ cosv,
                            const float* __restrict__ filt,
                            float* __restrict__ X,
                            unsigned* __restrict__ galloc) {
    __shared__ float s_r[N_DET];
    __shared__ float s_f[FILT_LEN];
    const int blk = blockIdx.x;            // b*N_ANG + a
    const int b   = blk / N_ANG;
    const int a   = blk % N_ANG;
    const int tid = threadIdx.x;

    if (blk == 0 && tid < NPART) galloc[tid] = 0u;

    for (int i = tid; i < N_DET; i += blockDim.x)
        s_r[i] = sin_fan[(size_t)(b * N_ANG + a) * N_DET + i] * cosv[a * N_DET + i];
    for (int i = tid; i < FILT_LEN; i += blockDim.x)
        s_f[i] = filt[i];
    __syncthreads();

    for (int d = tid; d < N_DET; d += blockDim.x) {
        float acc = 0.f;
        const float* fp = &s_f[356 - d];
        #pragma unroll 7
        for (int j = 0; j < N_DET; ++j)
            acc = fmaf(s_r[j], fp[j], acc);
        X[(size_t)(a * N_DET + d) * NB + b] = acc;
    }
}

// ---------------------------------------------------------------------------
// Single-pass binning WITH PRE-MULTIPLICATION (round-12 version — the 80us
// config; the r13 vmcnt-overlap rewrite regressed to 90us and was reverted).
// Stage phase: uint2 staging in LDS. Output phase: gather X4[col], quantize
// products at 2^20 into 14-bit signed fields, write ONE u64 entry
// [rl:8][i3:14][i2:14][i1:14][i0:14]. Accum then needs no gather.
// Run space reserved via galloc atomics; integer accumulation keeps results
// exactly deterministic regardless of allocation order.
// ---------------------------------------------------------------------------
__global__ void __launch_bounds__(1024)
bin1p_kernel(const float* __restrict__ A_vals,
             const int*   __restrict__ A_rows,
             const int*   __restrict__ A_cols,
             const float4* __restrict__ X4,
             unsigned* __restrict__ galloc,
             unsigned long long* __restrict__ bins) {
    __shared__ uint2 stage[CHUNK];            // 64 KB
    __shared__ unsigned char spart[CHUNK];    // 8 KB
    __shared__ unsigned loff[NPART], cnt[NPART], goff[NPART];
    const int chunk = blockIdx.x, tid = threadIdx.x;   // 1024
    if (tid < NPART) { cnt[tid] = 0; loff[tid] = 0; }
    __syncthreads();

    const int base = chunk * CHUNK;
    const int4*   r4 = (const int4*)(A_rows + base);
    const int4*   c4 = (const int4*)(A_cols + base);
    const float4* v4 = (const float4*)(A_vals + base);
    int rows[P2_PER_T];
    {
        const int4 ra = r4[tid * 2], rb = r4[tid * 2 + 1];
        rows[0] = ra.x; rows[1] = ra.y; rows[2] = ra.z; rows[3] = ra.w;
        rows[4] = rb.x; rows[5] = rb.y; rows[6] = rb.z; rows[7] = rb.w;
    }
    #pragma unroll
    for (int k = 0; k < P2_PER_T; ++k)
        atomicAdd(&loff[rows[k] >> PART_SH], 1u);      // histogram into loff
    __syncthreads();

    // reserve global run space (latency hides under the scan)
    unsigned hv = 0, gbase = 0;
    if (tid < NPART) {
        hv = loff[tid];
        gbase = atomicAdd(&galloc[tid], hv);
    }
    // exclusive scan loff in place (Hillis-Steele over first 256 threads)
    for (int off = 1; off < NPART; off <<= 1) {
        unsigned t = 0;
        if (tid < NPART && tid >= off) t = loff[tid - off];
        __syncthreads();
        if (tid < NPART) loff[tid] += t;
        __syncthreads();
    }
    if (tid < NPART) {
        loff[tid] -= hv;                               // inclusive -> exclusive
        goff[tid] = tid * CAPE + gbase;
    }
    __syncthreads();

    {
        const int4   ca = c4[tid * 2], cb = c4[tid * 2 + 1];
        const float4 va = v4[tid * 2], vb = v4[tid * 2 + 1];
        const unsigned cols[P2_PER_T] = {
            (unsigned)ca.x, (unsigned)ca.y, (unsigned)ca.z, (unsigned)ca.w,
            (unsigned)cb.x, (unsigned)cb.y, (unsigned)cb.z, (unsigned)cb.w };
        const float vals[P2_PER_T] = { va.x, va.y, va.z, va.w,
                                       vb.x, vb.y, vb.z, vb.w };
        #pragma unroll
        for (int k = 0; k < P2_PER_T; ++k) {
            const int row = rows[k];
            const int p = row >> PART_SH;
            const unsigned rank = atomicAdd(&cnt[p], 1u);
            const unsigned pos = loff[p] + rank;
            stage[pos] = make_uint2(__float_as_uint(vals[k]),
                                    ((unsigned)(row & (PART_PIX - 1)) << 17) | cols[k]);
            spart[pos] = (unsigned char)p;
        }
    }
    __syncthreads();

    #pragma unroll
    for (int k = 0; k < P2_PER_T; ++k) {
        const int i = k * P2_T + tid;
        const unsigned p = spart[i];
        const uint2 en = stage[i];
        const float v = __uint_as_float(en.x);
        const unsigned col = en.y & 0x1FFFFu;
        const unsigned long long rl = en.y >> 17;
        const float4 x = X4[col];
        const float c0 = fminf(fmaxf(v * x.x * FPS20, -8192.f), 8191.f);
        const float c1 = fminf(fmaxf(v * x.y * FPS20, -8192.f), 8191.f);
        const float c2 = fminf(fmaxf(v * x.z * FPS20, -8192.f), 8191.f);
        const float c3 = fminf(fmaxf(v * x.w * FPS20, -8192.f), 8191.f);
        const unsigned i0 = (unsigned)__float2int_rn(c0) & 0x3FFFu;
        const unsigned i1 = (unsigned)__float2int_rn(c1) & 0x3FFFu;
        const unsigned i2 = (unsigned)__float2int_rn(c2) & 0x3FFFu;
        const unsigned i3 = (unsigned)__float2int_rn(c3) & 0x3FFFu;
        const unsigned long long e =
            (rl << 56) | ((unsigned long long)i3 << 42) |
            ((unsigned long long)i2 << 28) | ((unsigned long long)i1 << 14) |
            (unsigned long long)i0;
        bins[goff[p] + (unsigned)i - loff[p]] = e;
    }
}

// ---------------------------------------------------------------------------
// Gather-free accum: coalesced u64 stream, decode 14-bit fields, 2 native
// ds_add_u64 per entry (2 channels packed per u64 at 2^20).
// ---------------------------------------------------------------------------
__device__ __forceinline__ int sx14(unsigned long long e, int sh) {
    return ((int)((((unsigned)(e >> sh)) & 0x3FFFu) << 18)) >> 18;
}

__global__ void __launch_bounds__(1024)
accum_pm_kernel(const unsigned long long* __restrict__ bins,
                const unsigned* __restrict__ galloc,
                unsigned long long* __restrict__ partial) {
    __shared__ unsigned long long iacc[2 * PART_PIX];   // 4 KB
    const int bp = blockIdx.x;
    const int p = bp >> 3, j = bp & 7;
    const int tid = threadIdx.x;
    if (tid < 2 * PART_PIX) iacc[tid] = 0ULL;
    __syncthreads();

    const unsigned c = galloc[p];
    const unsigned q = (c + ACC_SPLIT - 1) / ACC_SPLIT;
    const unsigned qs = j * q;
    const unsigned qe = min(qs + q, c);
    const unsigned long long* b8 = bins + (size_t)p * CAPE;

    #pragma unroll 4
    for (unsigned i = qs + tid; i < qe; i += 1024) {
        const unsigned long long e = b8[i];
        const unsigned rl = (unsigned)(e >> 56);
        const int i0 = sx14(e, 0);
        const int i1 = sx14(e, 14);
        const int i2 = sx14(e, 28);
        const int i3 = sx14(e, 42);
        const unsigned long long w0 =
            ((unsigned long long)(unsigned)i1 << 32) + (unsigned long long)(unsigned)i0;
        const unsigned long long w1 =
            ((unsigned long long)(unsigned)i3 << 32) + (unsigned long long)(unsigned)i2;
        atomicAdd(&iacc[rl], w0);
        atomicAdd(&iacc[PART_PIX + rl], w1);
    }
    __syncthreads();

    if (tid < 2 * PART_PIX)
        partial[((size_t)j * NPART + p) * (2 * PART_PIX) + tid] = iacc[tid];
}

// ---------------------------------------------------------------------------
// Sum the 8 u64 partials, decode both packed channels, clip, write.
// ---------------------------------------------------------------------------
__global__ void reduce8_kernel(const unsigned long long* __restrict__ partial,
                               float* __restrict__ out, float inv_scale) {
    const int g = blockIdx.x * blockDim.x + threadIdx.x;  // 0 .. 256*512-1
    const int p = g >> 9, t = g & 511;
    const int pair = t >> 8, rl = t & (PART_PIX - 1);
    unsigned long long s = 0;
    #pragma unroll
    for (int j = 0; j < ACC_SPLIT; ++j)
        s += partial[((size_t)j * NPART + p) * (2 * PART_PIX) + t];
    const float clo = (float)(int)(unsigned)(s & 0xffffffffULL) * inv_scale;
    const float chi = (float)(int)(unsigned)(s >> 32)           * inv_scale;
    const int ch0 = pair * 2, ch1 = pair * 2 + 1;
    out[(size_t)ch0 * N_PIXK + p * PART_PIX + rl] = fminf(fmaxf(clo, 0.f), 1.f);
    out[(size_t)ch1 * N_PIXK + p * PART_PIX + rl] = fminf(fmaxf(chi, 0.f), 1.f);
}

// ===================== fallback tier 2: round-8 sort path ==================
__global__ void filt2_kernel(const float* __restrict__ sin_fan,
                             const float* __restrict__ cosv,
                             const float* __restrict__ filt,
                             float* __restrict__ X) {
    __shared__ float s_r[N_DET];
    __shared__ float s_f[FILT_LEN];
    const int blk = blockIdx.x;
    const int b   = blk / N_ANG;
    const int a   = blk % N_ANG;
    const int tid = threadIdx.x;
    for (int i = tid; i < N_DET; i += blockDim.x)
        s_r[i] = sin_fan[(size_t)(b * N_ANG + a) * N_DET + i] * cosv[a * N_DET + i];
    for (int i = tid; i < FILT_LEN; i += blockDim.x)
        s_f[i] = filt[i];
    __syncthreads();
    for (int d = tid; d < N_DET; d += blockDim.x) {
        float acc = 0.f;
        const float* fp = &s_f[356 - d];
        #pragma unroll 7
        for (int j = 0; j < N_DET; ++j)
            acc = fmaf(s_r[j], fp[j], acc);
        X[(size_t)(a * N_DET + d) * NB + b] = acc;
    }
}

__global__ void hist_kernel(const int* __restrict__ A_rows,
                            unsigned* __restrict__ counts) {
    __shared__ unsigned h[NPART];
    const int chunk = blockIdx.x, tid = threadIdx.x;   // 256
    h[tid] = 0;
    __syncthreads();
    const int4* r4 = (const int4*)(A_rows + chunk * CHUNK);
    #pragma unroll
    for (int k = 0; k < 8; ++k) {
        const int4 rv = r4[tid * 8 + k];
        atomicAdd(&h[rv.x >> PART_SH], 1u);
        atomicAdd(&h[rv.y >> PART_SH], 1u);
        atomicAdd(&h[rv.z >> PART_SH], 1u);
        atomicAdd(&h[rv.w >> PART_SH], 1u);
    }
    __syncthreads();
    counts[chunk * NPART + tid] = h[tid];
}

__global__ void scanA_kernel(unsigned* __restrict__ counts,
                             unsigned* __restrict__ ptot) {
    const int p = blockIdx.x, tid = threadIdx.x;   // 256
    unsigned v[4], s = 0;
    #pragma unroll
    for (int k = 0; k < 4; ++k) {
        v[k] = counts[(size_t)(tid * 4 + k) * NPART + p];
        s += v[k];
    }
    __shared__ unsigned sc[256];
    sc[tid] = s;
    __syncthreads();
    for (int off = 1; off < 256; off <<= 1) {
        unsigned t = (tid >= off) ? sc[tid - off] : 0u;
        __syncthreads();
        sc[tid] += t;
        __syncthreads();
    }
    unsigned run = sc[tid] - s;
    if (tid == 255) ptot[p] = sc[255];
    #pragma unroll
    for (int k = 0; k < 4; ++k) {
        counts[(size_t)(tid * 4 + k) * NPART + p] = run;
        run += v[k];
    }
}

__global__ void scanB_kernel(const unsigned* __restrict__ ptot,
                             unsigned* __restrict__ part_base) {
    const int tid = threadIdx.x;                   // 256
    unsigned s = ptot[tid];
    __shared__ unsigned sc[256];
    sc[tid] = s;
    __syncthreads();
    for (int off = 1; off < 256; off <<= 1) {
        unsigned t = (tid >= off) ? sc[tid - off] : 0u;
        __syncthreads();
        sc[tid] += t;
        __syncthreads();
    }
    part_base[tid] = sc[tid] - s;
    if (tid == 255) part_base[256] = sc[255];
}

__global__ void __launch_bounds__(1024)
bin_kernel(const float* __restrict__ A_vals,
           const int*   __restrict__ A_rows,
           const int*   __restrict__ A_cols,
           const unsigned* __restrict__ offsets,
           const unsigned* __restrict__ part_base,
           uint2* __restrict__ bins) {
    __shared__ uint2 stage[CHUNK];
    __shared__ unsigned char spart[CHUNK];
    __shared__ unsigned loff[NPART], cnt[NPART], goff[NPART];
    const int chunk = blockIdx.x, tid = threadIdx.x;
    if (tid < NPART) cnt[tid] = 0;
    if (tid >= NPART && tid < 2 * NPART) loff[tid - NPART] = 0;
    __syncthreads();

    const int base = chunk * CHUNK;
    const int4*   r4 = (const int4*)(A_rows + base);
    const int4*   c4 = (const int4*)(A_cols + base);
    const float4* v4 = (const float4*)(A_vals + base);
    int rows[P2_PER_T];
    {
        const int4 ra = r4[tid * 2], rb = r4[tid * 2 + 1];
        rows[0] = ra.x; rows[1] = ra.y; rows[2] = ra.z; rows[3] = ra.w;
        rows[4] = rb.x; rows[5] = rb.y; rows[6] = rb.z; rows[7] = rb.w;
    }
    #pragma unroll
    for (int k = 0; k < P2_PER_T; ++k)
        atomicAdd(&loff[rows[k] >> PART_SH], 1u);
    __syncthreads();

    unsigned hv = 0;
    if (tid < NPART) hv = loff[tid];
    for (int off = 1; off < NPART; off <<= 1) {
        unsigned t = 0;
        if (tid < NPART && tid >= off) t = loff[tid - off];
        __syncthreads();
        if (tid < NPART) loff[tid] += t;
        __syncthreads();
    }
    if (tid < NPART) {
        loff[tid] -= hv;
        goff[tid] = part_base[tid] + offsets[chunk * NPART + tid];
    }
    __syncthreads();

    {
        const int4   ca = c4[tid * 2], cb = c4[tid * 2 + 1];
        const float4 va = v4[tid * 2], vb = v4[tid * 2 + 1];
        const unsigned cols[P2_PER_T] = {
            (unsigned)ca.x, (unsigned)ca.y, (unsigned)ca.z, (unsigned)ca.w,
            (unsigned)cb.x, (unsigned)cb.y, (unsigned)cb.z, (unsigned)cb.w };
        const float vals[P2_PER_T] = { va.x, va.y, va.z, va.w,
                                       vb.x, vb.y, vb.z, vb.w };
        #pragma unroll
        for (int k = 0; k < P2_PER_T; ++k) {
            const int row = rows[k];
            const int p = row >> PART_SH;
            const unsigned rank = atomicAdd(&cnt[p], 1u);
            const unsigned pos = loff[p] + rank;
            stage[pos] = make_uint2(__float_as_uint(vals[k]),
                                    ((unsigned)(row & (PART_PIX - 1)) << 17) | cols[k]);
            spart[pos] = (unsigned char)p;
        }
    }
    __syncthreads();

    #pragma unroll
    for (int k = 0; k < P2_PER_T; ++k) {
        const int i = k * P2_T + tid;
        const unsigned p = spart[i];
        const unsigned glob = goff[p] + (unsigned)i - loff[p];
        bins[glob] = stage[i];
    }
}

__global__ void __launch_bounds__(1024)
accum8_kernel(const uint2* __restrict__ bins,
              const unsigned* __restrict__ part_base,
              const float4* __restrict__ X4,
              unsigned long long* __restrict__ partial) {
    __shared__ unsigned long long iacc[2 * PART_PIX];
    const int bp = blockIdx.x;
    const int p = bp >> 3, j = bp & 7;
    const int tid = threadIdx.x;
    if (tid < 2 * PART_PIX) iacc[tid] = 0ULL;
    __syncthreads();

    const unsigned s = part_base[p], e = part_base[p + 1];
    const unsigned len = e - s;
    const unsigned q = (len + ACC_SPLIT - 1) / ACC_SPLIT;
    const unsigned qs = s + j * q;
    const unsigned qe = min(qs + q, e);

    #pragma unroll 4
    for (unsigned i = qs + tid; i < qe; i += 1024) {
        const uint2 en = bins[i];
        const float v = __uint_as_float(en.x);
        const unsigned col = en.y & 0x1FFFFu;
        const unsigned rl  = en.y >> 17;
        const float4 x = X4[col];
        const int i0 = __float2int_rn(v * x.x * FPS);
        const int i1 = __float2int_rn(v * x.y * FPS);
        const int i2 = __float2int_rn(v * x.z * FPS);
        const int i3 = __float2int_rn(v * x.w * FPS);
        const unsigned long long w0 =
            ((unsigned long long)(unsigned)i1 << 32) + (unsigned long long)(unsigned)i0;
        const unsigned long long w1 =
            ((unsigned long long)(unsigned)i3 << 32) + (unsigned long long)(unsigned)i2;
        atomicAdd(&iacc[rl], w0);
        atomicAdd(&iacc[PART_PIX + rl], w1);
    }
    __syncthreads();

    if (tid < 2 * PART_PIX)
        partial[((size_t)j * NPART + p) * (2 * PART_PIX) + tid] = iacc[tid];
}

// ===================== fallback tier 3: replica atomic path ================
#define NXCD 8
#define FP_SCALE 16777216.0f
#define FP_INV   (1.0 / 16777216.0)
__global__ void zero_u64_kernel(unsigned long long* __restrict__ p, int n) {
    int i = blockIdx.x * blockDim.x + threadIdx.x;
    if (i < n) p[i] = 0ULL;
}
__device__ __forceinline__ unsigned get_xcc_id() {
    unsigned x;
    asm volatile("s_getreg_b32 %0, hwreg(HW_REG_XCC_ID, 0, 4)" : "=s"(x));
    return x & (NXCD - 1);
}
__global__ void scatter_kernel(const float*  __restrict__ A_vals,
                               const int*    __restrict__ A_rows,
                               const int*    __restrict__ A_cols,
                               const float4* __restrict__ X4,
                               unsigned long long* __restrict__ rep) {
    unsigned long long* myrep = rep + (size_t)get_xcc_id() * N_PIXK * 2;
    const int stride = gridDim.x * blockDim.x;
    for (int i = blockIdx.x * blockDim.x + threadIdx.x; i < NNZK; i += stride) {
        const float v = A_vals[i];
        const float4 x = X4[A_cols[i]];
        const int r = A_rows[i];
        const int i0 = __float2int_rn(v * x.x * FP_SCALE);
        const int i1 = __float2int_rn(v * x.y * FP_SCALE);
        const int i2 = __float2int_rn(v * x.z * FP_SCALE);
        const int i3 = __float2int_rn(v * x.w * FP_SCALE);
        const unsigned long long w0 =
            ((unsigned long long)(unsigned)i1 << 32) + (unsigned long long)(unsigned)i0;
        const unsigned long long w1 =
            ((unsigned long long)(unsigned)i3 << 32) + (unsigned long long)(unsigned)i2;
        __hip_atomic_fetch_add(&myrep[(size_t)r * 2 + 0], w0,
                               __ATOMIC_RELAXED, __HIP_MEMORY_SCOPE_WORKGROUP);
        __hip_atomic_fetch_add(&myrep[(size_t)r * 2 + 1], w1,
                               __ATOMIC_RELAXED, __HIP_MEMORY_SCOPE_WORKGROUP);
    }
}
__global__ void reduce_clip_kernel(const unsigned long long* __restrict__ rep,
                                   float* __restrict__ out) {
    const int p = blockIdx.x * blockDim.x + threadIdx.x;
    if (p >= N_PIXK) return;
    unsigned long long s0 = 0, s1 = 0;
    #pragma unroll
    for (int x = 0; x < NXCD; ++x) {
        s0 += rep[((size_t)x * N_PIXK + p) * 2 + 0];
        s1 += rep[((size_t)x * N_PIXK + p) * 2 + 1];
    }
    const float c0 = (float)((double)(int)(unsigned)(s0 & 0xffffffffULL) * FP_INV);
    const float c1 = (float)((double)(int)(unsigned)(s0 >> 32)           * FP_INV);
    const float c2 = (float)((double)(int)(unsigned)(s1 & 0xffffffffULL) * FP_INV);
    const float c3 = (float)((double)(int)(unsigned)(s1 >> 32)           * FP_INV);
    out[0 * N_PIXK + p] = fminf(fmaxf(c0, 0.f), 1.f);
    out[1 * N_PIXK + p] = fminf(fmaxf(c1, 0.f), 1.f);
    out[2 * N_PIXK + p] = fminf(fmaxf(c2, 0.f), 1.f);
    out[3 * N_PIXK + p] = fminf(fmaxf(c3, 0.f), 1.f);
}

extern "C" void kernel_launch(void* const* d_in, const int* in_sizes, int n_in,
                              void* d_out, int out_size, void* d_ws, size_t ws_size,
                              hipStream_t stream) {
    const float* sin_fan = (const float*)d_in[0];
    const float* cosv    = (const float*)d_in[1];
    const float* filt    = (const float*)d_in[2];
    const float* A_vals  = (const float*)d_in[3];
    const int*   A_rows  = (const int*)d_in[4];
    const int*   A_cols  = (const int*)d_in[5];
    float* out = (float*)d_out;

    const size_t MB = 1024 * 1024;
    // --- tier 1: pre-multiplied single-pass layout ---
    const size_t off_alloc = 2 * MB;
    const size_t off_part  = off_alloc + 65536;
    const size_t off_bins  = off_part +
        (size_t)ACC_SPLIT * NPART * (2 * PART_PIX) * sizeof(unsigned long long);
    const size_t need_1p   = off_bins +
        (size_t)NPART * CAPE * sizeof(unsigned long long);
    // --- tier 2 (round-8) layout ---
    const size_t need_sort  = 3 * MB + 4096 + (size_t)NNZK * sizeof(uint2);
    const size_t need_split = need_sort +
        (size_t)ACC_SPLIT * NPART * (2 * PART_PIX) * sizeof(unsigned long long);

    if (ws_size >= need_1p) {
        float*    X      = (float*)d_ws;
        unsigned* galloc = (unsigned*)((char*)d_ws + off_alloc);
        unsigned long long* partial =
            (unsigned long long*)((char*)d_ws + off_part);
        unsigned long long* bins =
            (unsigned long long*)((char*)d_ws + off_bins);

        filt_kernel<<<NB * N_ANG, 256, 0, stream>>>(sin_fan, cosv, filt, X,
                                                    galloc);
        bin1p_kernel<<<NCHUNK, P2_T, 0, stream>>>(A_vals, A_rows, A_cols,
                                                  (const float4*)X, galloc, bins);
        accum_pm_kernel<<<NPART * ACC_SPLIT, 1024, 0, stream>>>(
            bins, galloc, partial);
        reduce8_kernel<<<(NPART * 2 * PART_PIX) / 1024, 1024, 0, stream>>>(
            partial, out, FPS20_INV);
    } else if (ws_size >= need_split) {
        float*    X      = (float*)d_ws;
        unsigned* counts = (unsigned*)((char*)d_ws + 2 * MB);
        unsigned* pbase  = (unsigned*)((char*)d_ws + 3 * MB);
        unsigned* ptot   = (unsigned*)((char*)d_ws + 3 * MB + 2048);
        uint2*    bins   = (uint2*)((char*)d_ws + 3 * MB + 4096);
        unsigned long long* partial =
            (unsigned long long*)((char*)d_ws + need_sort);

        filt2_kernel<<<NB * N_ANG, 256, 0, stream>>>(sin_fan, cosv, filt, X);
        hist_kernel<<<NCHUNK, P1_T, 0, stream>>>(A_rows, counts);
        scanA_kernel<<<NPART, 256, 0, stream>>>(counts, ptot);
        scanB_kernel<<<1, 256, 0, stream>>>(ptot, pbase);
        bin_kernel<<<NCHUNK, P2_T, 0, stream>>>(A_vals, A_rows, A_cols, counts,
                                                pbase, bins);
        accum8_kernel<<<NPART * ACC_SPLIT, 1024, 0, stream>>>(
            bins, pbase, (const float4*)X, partial);
        reduce8_kernel<<<(NPART * 2 * PART_PIX) / 1024, 1024, 0, stream>>>(
            partial, out, FPS_INV);
    } else {
        unsigned long long* rep = (unsigned long long*)d_ws;
        const size_t rep_bytes = (size_t)NXCD * N_PIXK * 2 * sizeof(unsigned long long);
        float* X = (float*)((char*)d_ws + rep_bytes);
        const int nrep = NXCD * N_PIXK * 2;
        zero_u64_kernel<<<(nrep + 255) / 256, 256, 0, stream>>>(rep, nrep);
        filt2_kernel<<<NB * N_ANG, 256, 0, stream>>>(sin_fan, cosv, filt, X);
        scatter_kernel<<<4096, 256, 0, stream>>>(A_vals, A_rows, A_cols,
                                                 (const float4*)X, rep);
        reduce_clip_kernel<<<(N_PIXK + 255) / 256, 256, 0, stream>>>(rep, out);
    }
}